// Round 13
// baseline (425.450 us; speedup 1.0000x reference)
//
#include <hip/hip_runtime.h>
#include <hip/hip_bf16.h>

// EdgeConv block: B=8 clouds, N=4096 pts, K=20 nn, C_IN=64, C_OUT=128.
// Key identity: e@W1 = [xi | xj-xi]@W1 = xi@Wa + xj@Wb  (Wa=W1top-W1bot, Wb=W1bot)
// Pipeline: k_prep (x -> bf16 hi/lo planes + sqn=-0.5*|x|^2) -> k_wt
//   -> k_knn (1024 blocks x 32 queries; cand-hi-only MFMA distances; packed-idx
//             med3 top-20; 16-list 2-round merge -> top-28; exact fp32 recheck)
//   -> k_ybres (Yb = x@Wb bf16; out = x@Wres + bres, one kernel)
//   -> k_edge (Ya in-block MFMA; v=Ya[p]+Yb[j]; LN1; GEMM2(W2 LDS packed); LN2; max; add)

#define NB 8
#define NPTS 4096
#define KNN 20
#define NTOT (NB * NPTS)       // 32768
#define NEDGE (NTOT * KNN)     // 655360
#define LDA 136                // bf16 row stride (128 + 8 pad) -> 272 B
#define RB 28                  // recheck buffer size

typedef short bf16x8 __attribute__((ext_vector_type(8)));
typedef float f32x4 __attribute__((ext_vector_type(4)));

__device__ __forceinline__ unsigned short f2bf(float f) {
    union { float f; unsigned u; } v; v.f = f;
    unsigned r = v.u + 0x7FFFu + ((v.u >> 16) & 1u);   // RTNE
    return (unsigned short)(r >> 16);
}
__device__ __forceinline__ float bf2f(unsigned short s) {
    union { unsigned u; float f; } v; v.u = ((unsigned)s) << 16;
    return v.f;
}

// ---------------- x -> bf16 hi/lo planes + sqn = -0.5*rowsum(x^2) ----------------
__global__ __launch_bounds__(256) void k_prep(const float* __restrict__ x,
                                              unsigned short* __restrict__ xhi,
                                              unsigned short* __restrict__ xlo,
                                              float* __restrict__ sqn) {
    int id = blockIdx.x * 2048 + threadIdx.x * 8;
    float4 v0 = *(const float4*)(x + id);
    float4 v1 = *(const float4*)(x + id + 4);
    float vs[8] = {v0.x, v0.y, v0.z, v0.w, v1.x, v1.y, v1.z, v1.w};
    unsigned short h[8], l[8];
    float s = 0.f;
#pragma unroll
    for (int i = 0; i < 8; ++i) {
        h[i] = f2bf(vs[i]);
        l[i] = f2bf(vs[i] - bf2f(h[i]));
        s += vs[i] * vs[i];
    }
    uint4 hp, lp;
    hp.x = h[0] | ((unsigned)h[1] << 16); hp.y = h[2] | ((unsigned)h[3] << 16);
    hp.z = h[4] | ((unsigned)h[5] << 16); hp.w = h[6] | ((unsigned)h[7] << 16);
    lp.x = l[0] | ((unsigned)l[1] << 16); lp.y = l[2] | ((unsigned)l[3] << 16);
    lp.z = l[4] | ((unsigned)l[5] << 16); lp.w = l[6] | ((unsigned)l[7] << 16);
    *(uint4*)(xhi + id) = hp;
    *(uint4*)(xlo + id) = lp;
    s += __shfl_xor(s, 1); s += __shfl_xor(s, 2); s += __shfl_xor(s, 4);
    if ((threadIdx.x & 7) == 0) sqn[id >> 6] = -0.5f * s;
}

// ---------------- weights: Wa/Wb/Wres transposed bf16 + W2 frag-packed ----------------
__global__ __launch_bounds__(256) void k_wt(const float* __restrict__ W1, const float* __restrict__ W2,
                                            const float* __restrict__ Wres,
                                            unsigned short* __restrict__ wa, unsigned short* __restrict__ wb,
                                            unsigned short* __restrict__ wrt, unsigned short* __restrict__ w2p) {
    int id = blockIdx.x * 256 + threadIdx.x;   // 0..40959
    if (id < 16384) {
        int f = id >> 9, pos = id & 511;
        int lane = pos >> 3, m = pos & 7;
        int ks = f >> 3, nt = f & 7;
        int lr = lane & 15, kg = lane >> 4;
        int c = ks * 32 + kg * 8 + m;
        int d = nt * 16 + lr;
        w2p[id] = f2bf(W2[c * 128 + d]);
    } else if (id < 24576) {
        int i = id - 16384;
        int d = i >> 6, c = i & 63;
        wa[i] = f2bf(W1[c * 128 + d] - W1[(64 + c) * 128 + d]);
    } else if (id < 32768) {
        int i = id - 24576;
        int d = i >> 6, c = i & 63;
        wb[i] = f2bf(W1[(64 + c) * 128 + d]);
    } else {
        int i = id - 32768;
        int d = i >> 6, c = i & 63;
        wrt[i] = f2bf(Wres[c * 128 + d]);
    }
}

// ---------------- KNN via MFMA: 1024 blocks x 32 queries, 4 blocks/CU ----------------
// Waves: (qgrp = w>>2) x (tp = w&3). Super s covers tiles 4s+tp (32 cands each);
// 32 supers, 1 barrier each. Candidate side uses hi plane only (score error
// |clo.q| ~0.02 << rank spacing; absorbed by RB=28 exact-recheck buffer).
// Lane (lr=query, kg) streams 256 cands: packed (score|idx12) med3 top-20.
// Epilogue: 16 lists merged in 2 rounds of 8 -> top-28 -> exact fp32 recheck
// -> drop 8 lexicographically-largest -> exact top-20 set.
__global__ __launch_bounds__(512, 4) void k_knn(const float* __restrict__ x,
                                                const unsigned short* __restrict__ xhi,
                                                const unsigned short* __restrict__ xlo,
                                                const float* __restrict__ sqn,
                                                int* __restrict__ knn_idx) {
    int b  = blockIdx.x & 7;           // cloud -> XCD pinning (1024 % 8 == 0)
    int qb = blockIdx.x >> 3;          // 0..127
    int t  = threadIdx.x;
    int w = t >> 6, lane = t & 63;
    int lr = lane & 15, kg = lane >> 4;
    int qgrp = w >> 2, tp = w & 3;
    int n0  = b * NPTS + qb * 32;
    int cb0 = b * NPTS;

    // LDS liveness union (36480 B total -> 4 blocks/CU):
    //   stream: ring 32768 B; merge: md (20608 B, stride-161); recheck: ce overlays
    __shared__ union {
        unsigned short ring[2][4][4][512];   // [buf][tile-in-super][frag(st*2+kh)][shorts]
        struct { float md[32][161]; } m;     // 8 lists x 20 per round, row-padded
        struct { float ce[32][29]; } r;
    } U;
    __shared__ int ci[32][29];

    // query B-fragments (col = lane&15, k-slice kg*8), hi/lo x 2 K-halves
    int qg = n0 + qgrp * 16 + lr;
    bf16x8 qhi0 = *(const bf16x8*)(xhi + (size_t)qg * 64 + kg * 8);
    bf16x8 qhi1 = *(const bf16x8*)(xhi + (size_t)qg * 64 + 32 + kg * 8);
    bf16x8 qlo0 = *(const bf16x8*)(xlo + (size_t)qg * 64 + kg * 8);
    bf16x8 qlo1 = *(const bf16x8*)(xlo + (size_t)qg * 64 + 32 + kg * 8);

    // staging: wave (qgrp,tp) stages frags {2qgrp, 2qgrp+1} (subtile qgrp, both K-halves)
    // of tile tp; per-lane source: row = qgrp*16+lr, k = kg*8 (+32 for kh=1)
    size_t soff = (size_t)(qgrp * 16 + lr) * 64 + kg * 8;

    float kd[KNN];
#pragma unroll
    for (int p = 0; p < KNN; ++p) kd[p] = 3.4e38f;
    int myq = qgrp * 16 + lr;

    // prologue: stage super 0; prefetch super 1
    {
        const unsigned short* sp = xhi + (size_t)(cb0 + tp * 32) * 64 + soff;
        uint4 p0 = *(const uint4*)sp;
        uint4 p1 = *(const uint4*)(sp + 32);
        *(uint4*)&U.ring[0][tp][2 * qgrp][lane * 8] = p0;
        *(uint4*)&U.ring[0][tp][2 * qgrp + 1][lane * 8] = p1;
    }
    uint4 g0, g1;
    {
        const unsigned short* sp = xhi + (size_t)(cb0 + (4 + tp) * 32) * 64 + soff;
        g0 = *(const uint4*)sp;
        g1 = *(const uint4*)(sp + 32);
    }
    __syncthreads();

#pragma unroll 1
    for (int s = 0; s < 32; ++s) {
        int cbT = cb0 + (4 * s + tp) * 32;
        if (s + 1 < 32) {                      // publish prefetched super s+1
            *(uint4*)&U.ring[(s + 1) & 1][tp][2 * qgrp][lane * 8] = g0;
            *(uint4*)&U.ring[(s + 1) & 1][tp][2 * qgrp + 1][lane * 8] = g1;
        }
        if (s + 2 < 32) {                      // issue loads for super s+2
            const unsigned short* sp = xhi + (size_t)(cb0 + (4 * (s + 2) + tp) * 32) * 64 + soff;
            g0 = *(const uint4*)sp;
            g1 = *(const uint4*)(sp + 32);
        }

        // C-init = sqn (L1-hot direct load; no prefetch regs -> VGPR <= 64)
        f32x4 a00 = *(const f32x4*)&sqn[cbT + kg * 4];
        f32x4 a10 = *(const f32x4*)&sqn[cbT + 16 + kg * 4];
        f32x4 a01 = {0.f, 0.f, 0.f, 0.f};
        f32x4 a11 = {0.f, 0.f, 0.f, 0.f};

        const unsigned short* fr = &U.ring[s & 1][tp][0][0];
        bf16x8 A0 = *(const bf16x8*)(fr + 0 * 512 + lane * 8);   // st0 kh0
        bf16x8 A1 = *(const bf16x8*)(fr + 1 * 512 + lane * 8);   // st0 kh1
        bf16x8 A2 = *(const bf16x8*)(fr + 2 * 512 + lane * 8);   // st1 kh0
        bf16x8 A3 = *(const bf16x8*)(fr + 3 * 512 + lane * 8);   // st1 kh1

        // dot = chi.(qhi+qlo): 8 MFMAs, 4 independent chains of 2
        a00 = __builtin_amdgcn_mfma_f32_16x16x32_bf16(A0, qhi0, a00, 0, 0, 0);
        a10 = __builtin_amdgcn_mfma_f32_16x16x32_bf16(A2, qhi0, a10, 0, 0, 0);
        a01 = __builtin_amdgcn_mfma_f32_16x16x32_bf16(A1, qhi1, a01, 0, 0, 0);
        a11 = __builtin_amdgcn_mfma_f32_16x16x32_bf16(A3, qhi1, a11, 0, 0, 0);
        a00 = __builtin_amdgcn_mfma_f32_16x16x32_bf16(A0, qlo0, a00, 0, 0, 0);
        a10 = __builtin_amdgcn_mfma_f32_16x16x32_bf16(A2, qlo0, a10, 0, 0, 0);
        a01 = __builtin_amdgcn_mfma_f32_16x16x32_bf16(A1, qlo1, a01, 0, 0, 0);
        a11 = __builtin_amdgcn_mfma_f32_16x16x32_bf16(A3, qlo1, a11, 0, 0, 0);

        int ibase = (4 * s + tp) * 32 + kg * 4;
#pragma unroll
        for (int j = 0; j < 8; ++j) {
            float sc = (j < 4) ? -(a00[j & 3] + a01[j & 3]) : -(a10[j & 3] + a11[j & 3]);
            unsigned idx12 = (unsigned)(ibase + ((j >> 2) << 4) + (j & 3));
            float xv = __uint_as_float((__float_as_uint(sc) & 0xFFFFF000u) | idx12);
#pragma unroll
            for (int p = KNN - 1; p >= 1; --p)
                kd[p] = __builtin_amdgcn_fmed3f(xv, kd[p - 1], kd[p]);
            kd[0] = fminf(kd[0], xv);
        }

        __syncthreads();
    }

    // ---- 2-round 16-list merge (md overlays dead ring) ----
    float kdm[RB];
    float km = 3.4e38f;

    if (tp < 2) {                              // round A lists: tp in {0,1}
#pragma unroll
        for (int p = 0; p < KNN; ++p)
            U.m.md[myq][(tp * 4 + kg) * KNN + p] = kd[p];
    }
    __syncthreads();
    if (t < 32) {
#pragma unroll
        for (int s2 = 0; s2 < RB; ++s2) kdm[s2] = 3.4e38f;
#pragma unroll 1
        for (int u = 0; u < 8; ++u) {
#pragma unroll 1
            for (int p = 0; p < KNN; ++p) {
                float d = U.m.md[t][u * KNN + p];
                if (d >= km) break;            // ascending list: rest can't qualify
#pragma unroll
                for (int s2 = RB - 1; s2 >= 1; --s2)
                    kdm[s2] = __builtin_amdgcn_fmed3f(d, kdm[s2 - 1], kdm[s2]);
                kdm[0] = fminf(kdm[0], d);
                km = kdm[RB - 1];
            }
        }
    }
    __syncthreads();
    if (tp >= 2) {                             // round B lists: tp in {2,3}
#pragma unroll
        for (int p = 0; p < KNN; ++p)
            U.m.md[myq][((tp - 2) * 4 + kg) * KNN + p] = kd[p];
    }
    __syncthreads();
    if (t < 32) {
#pragma unroll 1
        for (int u = 0; u < 8; ++u) {
#pragma unroll 1
            for (int p = 0; p < KNN; ++p) {
                float d = U.m.md[t][u * KNN + p];
                if (d >= km) break;
#pragma unroll
                for (int s2 = RB - 1; s2 >= 1; --s2)
                    kdm[s2] = __builtin_amdgcn_fmed3f(d, kdm[s2 - 1], kdm[s2]);
                kdm[0] = fminf(kdm[0], d);
                km = kdm[RB - 1];
            }
        }
#pragma unroll
        for (int s2 = 0; s2 < RB; ++s2)
            ci[t][s2] = (int)(__float_as_uint(kdm[s2]) & 0xFFFu) + cb0;
    }
    __syncthreads();   // md dead; ce overlays it

    // exact fp32 recheck: 32*28 = 896 tasks over 512 threads
#pragma unroll 1
    for (int task = t; task < 32 * RB; task += 512) {
        int q = task / RB, sl = task - q * RB;
        int cidx = ci[q][sl];
        const float* xqp = x + (size_t)(n0 + q) * 64;
        const float* xc  = x + (size_t)cidx * 64;
        float dot = 0.f;
#pragma unroll
        for (int g = 0; g < 16; ++g) {
            float4 a = *(const float4*)(xqp + g * 4);
            float4 bb = *(const float4*)(xc + g * 4);
            dot += a.x * bb.x + a.y * bb.y + a.z * bb.z + a.w * bb.w;
        }
        U.r.ce[q][sl] = -sqn[cidx] - dot;     // = 0.5*sq - dot
    }
    __syncthreads();

    // drop the 8 lexicographically-largest (score, then higher idx) -> exact top-20 set
    if (t < 32) {
        float ev[RB]; int iv[RB];
#pragma unroll
        for (int s2 = 0; s2 < RB; ++s2) { ev[s2] = U.r.ce[t][s2]; iv[s2] = ci[t][s2]; }
        unsigned mask = 0;
#pragma unroll
        for (int pass = 0; pass < RB - KNN; ++pass) {
            float best = -3.4e38f; int bid = -1, bs = 0;
#pragma unroll
            for (int s2 = 0; s2 < RB; ++s2) {
                bool free_ = ((mask >> s2) & 1u) == 0u;
                bool gt = (ev[s2] > best) || (ev[s2] == best && iv[s2] > bid);
                if (free_ && gt) { best = ev[s2]; bid = iv[s2]; bs = s2; }
            }
            mask |= 1u << bs;
        }
        int* op = knn_idx + (size_t)(n0 + t) * KNN;
        int pos = 0;
#pragma unroll
        for (int s2 = 0; s2 < RB; ++s2)
            if (((mask >> s2) & 1u) == 0u) op[pos++] = iv[s2];
    }
}

// ---------------- fused Yb = x@Wb (bf16) and out = x@Wres + bres ----------------
__global__ __launch_bounds__(256) void k_ybres(const unsigned short* __restrict__ xhi,
                                               const unsigned short* __restrict__ wb,
                                               const unsigned short* __restrict__ wrt,
                                               const float* __restrict__ bres,
                                               unsigned short* __restrict__ Yb,
                                               float* __restrict__ out) {
    int t = threadIdx.x;
    int wv = t >> 6, lane = t & 63;
    int lr = lane & 15, kg = lane >> 4;
    int n0 = blockIdx.x * 64 + wv * 16;

    bf16x8 af0 = *(const bf16x8*)(xhi + (size_t)(n0 + lr) * 64 + kg * 8);
    bf16x8 af1 = *(const bf16x8*)(xhi + (size_t)(n0 + lr) * 64 + 32 + kg * 8);

    f32x4 accY[8], accR[8];
#pragma unroll
    for (int nt = 0; nt < 8; ++nt) {
        accY[nt] = (f32x4){0.f, 0.f, 0.f, 0.f};
        float bv = bres[nt * 16 + lr];
        accR[nt] = (f32x4){bv, bv, bv, bv};
    }
#pragma unroll
    for (int nt = 0; nt < 8; ++nt) {
        bf16x8 b0 = *(const bf16x8*)(wb + (size_t)(nt * 16 + lr) * 64 + kg * 8);
        bf16x8 b1 = *(const bf16x8*)(wb + (size_t)(nt * 16 + lr) * 64 + 32 + kg * 8);
        accY[nt] = __builtin_amdgcn_mfma_f32_16x16x32_bf16(af0, b0, accY[nt], 0, 0, 0);
        accY[nt] = __builtin_amdgcn_mfma_f32_16x16x32_bf16(af1, b1, accY[nt], 0, 0, 0);
        bf16x8 r0 = *(const bf16x8*)(wrt + (size_t)(nt * 16 + lr) * 64 + kg * 8);
        bf16x8 r1 = *(const bf16x8*)(wrt + (size_t)(nt * 16 + lr) * 64 + 32 + kg * 8);
        accR[nt] = __builtin_amdgcn_mfma_f32_16x16x32_bf16(af0, r0, accR[nt], 0, 0, 0);
        accR[nt] = __builtin_amdgcn_mfma_f32_16x16x32_bf16(af1, r1, accR[nt], 0, 0, 0);
    }
#pragma unroll
    for (int nt = 0; nt < 8; ++nt)
#pragma unroll
        for (int j = 0; j < 4; ++j) {
            Yb[(size_t)(n0 + kg * 4 + j) * 128 + nt * 16 + lr] = f2bf(accY[nt][j]);
            out[(size_t)(n0 + kg * 4 + j) * 128 + nt * 16 + lr] = accR[nt][j];
        }
}

// ---------------- LN2 helper (C-frag layout; wave-local rows) ----------------
__device__ __forceinline__ void ln_relu_store(f32x4 acc[2][8], unsigned short* A, int wv, int lane,
                                              const float* __restrict__ bias, const float* __restrict__ g,
                                              const float* __restrict__ be) {
    int lc = lane & 15, kg = lane >> 4;
    float bv[8], gv[8], bev[8];
#pragma unroll
    for (int nt = 0; nt < 8; ++nt) {
        bv[nt]  = bias[nt * 16 + lc];
        gv[nt]  = g[nt * 16 + lc];
        bev[nt] = be[nt * 16 + lc];
    }
#pragma unroll
    for (int mt = 0; mt < 2; ++mt) {
#pragma unroll
        for (int j = 0; j < 4; ++j) {
            float v[8]; float s = 0.f, ss = 0.f;
#pragma unroll
            for (int nt = 0; nt < 8; ++nt) {
                v[nt] = acc[mt][nt][j] + bv[nt];
                s += v[nt]; ss += v[nt] * v[nt];
            }
#pragma unroll
            for (int m = 1; m < 16; m <<= 1) { s += __shfl_xor(s, m); ss += __shfl_xor(ss, m); }
            float mean = s * 0.0078125f;
            float var  = ss * 0.0078125f - mean * mean;
            float rstd = rsqrtf(fmaxf(var, 0.f) + 1e-5f);
            int row = wv * 32 + mt * 16 + kg * 4 + j;
#pragma unroll
            for (int nt = 0; nt < 8; ++nt) {
                float h = (v[nt] - mean) * rstd * gv[nt] + bev[nt];
                h = fmaxf(h, 0.f);
                A[(size_t)row * LDA + nt * 16 + lc] = f2bf(h);
            }
        }
    }
}

// ---------------- fused edge kernel (no GEMM1) ----------------
__global__ __launch_bounds__(320, 2) void k_edge(const float* __restrict__ x, const int* __restrict__ knn_idx,
                                                 const unsigned short* __restrict__ Yb,
                                                 const unsigned short* __restrict__ w2p,
                                                 const unsigned short* __restrict__ wa,
                                                 const float* __restrict__ b1, const float* __restrict__ g1, const float* __restrict__ be1,
                                                 const float* __restrict__ b2, const float* __restrict__ g2, const float* __restrict__ be2,
                                                 float* __restrict__ out) {
    __shared__ unsigned short A[160 * LDA];    // 43520 B: h1 -> h2
    __shared__ unsigned short W2s[32 * 512];   // 32768 B: W2 frag-packed
    __shared__ float Ya8[8][128];              // 4096 B
    __shared__ float GB[256];                  // g1 | be1
    int t = threadIdx.x;
    int bid = blockIdx.x;
    int blk = (bid & 7) * 512 + (bid >> 3);    // XCD swizzle: cloud-pinned

    for (int id = t; id < 2048; id += 320)
        *(uint4*)&W2s[id * 8] = *(const uint4*)(w2p + (size_t)id * 8);
    if (t < 32)       *(float4*)&GB[t * 4] = *(const float4*)(g1 + t * 4);
    else if (t < 64)  *(float4*)&GB[t * 4] = *(const float4*)(be1 + (t - 32) * 4);

    int r = t >> 1, h = t & 1;
    int eg = blk * 160 + r;
    int ploc = r / 20;
    int jn = knn_idx[eg];
    uint4 ybr[8];
    {
        const unsigned short* ybp = Yb + (size_t)jn * 128 + h * 64;
#pragma unroll
        for (int i = 0; i < 8; ++i) ybr[i] = *(const uint4*)(ybp + i * 8);
    }

    if (t < 64) {
        int lane = t, lr = lane & 15, kg = lane >> 4;
        int prow = blk * 8 + (lr & 7);
        const float* xp = x + (size_t)prow * 64;
        bf16x8 af0, af1;
        {
            union { unsigned short u[8]; bf16x8 v; } cv;
            float4 u0 = *(const float4*)(xp + kg * 8);
            float4 u1 = *(const float4*)(xp + kg * 8 + 4);
            cv.u[0] = f2bf(u0.x); cv.u[1] = f2bf(u0.y); cv.u[2] = f2bf(u0.z); cv.u[3] = f2bf(u0.w);
            cv.u[4] = f2bf(u1.x); cv.u[5] = f2bf(u1.y); cv.u[6] = f2bf(u1.z); cv.u[7] = f2bf(u1.w);
            af0 = cv.v;
            float4 w0 = *(const float4*)(xp + 32 + kg * 8);
            float4 w1 = *(const float4*)(xp + 32 + kg * 8 + 4);
            cv.u[0] = f2bf(w0.x); cv.u[1] = f2bf(w0.y); cv.u[2] = f2bf(w0.z); cv.u[3] = f2bf(w0.w);
            cv.u[4] = f2bf(w1.x); cv.u[5] = f2bf(w1.y); cv.u[6] = f2bf(w1.z); cv.u[7] = f2bf(w1.w);
            af1 = cv.v;
        }
        f32x4 accA[8];
#pragma unroll
        for (int nt = 0; nt < 8; ++nt) {
            float bv = b1[nt * 16 + lr];
            accA[nt] = (f32x4){bv, bv, bv, bv};
        }
#pragma unroll
        for (int nt = 0; nt < 8; ++nt) {
            bf16x8 b0 = *(const bf16x8*)(wa + (size_t)(nt * 16 + lr) * 64 + kg * 8);
            bf16x8 b1f = *(const bf16x8*)(wa + (size_t)(nt * 16 + lr) * 64 + 32 + kg * 8);
            accA[nt] = __builtin_amdgcn_mfma_f32_16x16x32_bf16(af0, b0, accA[nt], 0, 0, 0);
            accA[nt] = __builtin_amdgcn_mfma_f32_16x16x32_bf16(af1, b1f, accA[nt], 0, 0, 0);
        }
#pragma unroll
        for (int nt = 0; nt < 8; ++nt)
#pragma unroll
            for (int j = 0; j < 4; ++j) {
                int rr = kg * 4 + j;
                if (rr < 8) Ya8[rr][nt * 16 + lr] = accA[nt][j];
            }
    }
    __syncthreads();

    {
        float v[64]; float s = 0.f, ss = 0.f;
#pragma unroll
        for (int i = 0; i < 8; ++i) {
            unsigned uu[4] = {ybr[i].x, ybr[i].y, ybr[i].z, ybr[i].w};
#pragma unroll
            for (int k2 = 0; k2 < 4; ++k2) {
                int c = h * 64 + i * 8 + 2 * k2;
                float w0 = Ya8[ploc][c]     + bf2f((unsigned short)(uu[k2] & 0xFFFFu));
                float w1 = Ya8[ploc][c + 1] + bf2f((unsigned short)(uu[k2] >> 16));
                v[i * 8 + 2 * k2] = w0; v[i * 8 + 2 * k2 + 1] = w1;
                s += w0 + w1; ss += w0 * w0 + w1 * w1;
            }
        }
        s += __shfl_xor(s, 1); ss += __shfl_xor(ss, 1);
        float mean = s * 0.0078125f;
        float var  = ss * 0.0078125f - mean * mean;
        float rstd = rsqrtf(fmaxf(var, 0.f) + 1e-5f);
#pragma unroll
        for (int i = 0; i < 8; ++i) {
            unsigned short hh[8];
#pragma unroll
            for (int k2 = 0; k2 < 8; ++k2) {
                int c = h * 64 + i * 8 + k2;
                float hv = (v[i * 8 + k2] - mean) * rstd * GB[c] + GB[128 + c];
                hh[k2] = f2bf(fmaxf(hv, 0.f));
            }
            uint4 pk;
            pk.x = hh[0] | ((unsigned)hh[1] << 16); pk.y = hh[2] | ((unsigned)hh[3] << 16);
            pk.z = hh[4] | ((unsigned)hh[5] << 16); pk.w = hh[6] | ((unsigned)hh[7] << 16);
            *(uint4*)&A[(size_t)r * LDA + h * 64 + i * 8] = pk;
        }
    }

    int wv = t >> 6, lane = t & 63;
    int lr = lane & 15, kg = lane >> 4;
    f32x4 acc2[2][8];
#pragma unroll
    for (int i = 0; i < 2; ++i)
#pragma unroll
        for (int j = 0; j < 8; ++j) acc2[i][j] = (f32x4){0.f, 0.f, 0.f, 0.f};
#pragma unroll
    for (int ks = 0; ks < 4; ++ks) {
        int ko = ks * 32 + kg * 8;
        bf16x8 a0 = *(const bf16x8*)(A + (size_t)(wv * 32 + lr) * LDA + ko);
        bf16x8 a1 = *(const bf16x8*)(A + (size_t)(wv * 32 + 16 + lr) * LDA + ko);
#pragma unroll
        for (int nt = 0; nt < 8; ++nt) {
            bf16x8 bf = *(const bf16x8*)&W2s[(size_t)(ks * 8 + nt) * 512 + lane * 8];
            acc2[0][nt] = __builtin_amdgcn_mfma_f32_16x16x32_bf16(a0, bf, acc2[0][nt], 0, 0, 0);
            acc2[1][nt] = __builtin_amdgcn_mfma_f32_16x16x32_bf16(a1, bf, acc2[1][nt], 0, 0, 0);
        }
    }
    ln_relu_store(acc2, A, wv, lane, b2, g2, be2);

    __syncthreads();

    if (t < 128) {
        int p = t >> 4, cg = t & 15;
        int n = blk * 8 + p;
        float mx[8];
#pragma unroll
        for (int k = 0; k < 8; ++k) mx[k] = 0.f;
#pragma unroll
        for (int rr = 0; rr < 20; ++rr) {
            uint4 vv = *(const uint4*)&A[(size_t)(p * 20 + rr) * LDA + cg * 8];
            unsigned uu[4] = {vv.x, vv.y, vv.z, vv.w};
#pragma unroll
            for (int k = 0; k < 4; ++k) {
                float lo = __uint_as_float(uu[k] << 16);
                float hi = __uint_as_float(uu[k] & 0xFFFF0000u);
                mx[2 * k]     = fmaxf(mx[2 * k], lo);
                mx[2 * k + 1] = fmaxf(mx[2 * k + 1], hi);
            }
        }
        float* op = out + (size_t)n * 128 + cg * 8;
        float4 o0 = *(float4*)op;
        float4 o1 = *(float4*)(op + 4);
        o0.x += mx[0]; o0.y += mx[1]; o0.z += mx[2]; o0.w += mx[3];
        o1.x += mx[4]; o1.y += mx[5]; o1.z += mx[6]; o1.w += mx[7];
        *(float4*)op = o0;
        *(float4*)(op + 4) = o1;
    }
}

// ---------------- launcher ----------------
extern "C" void kernel_launch(void* const* d_in, const int* in_sizes, int n_in,
                              void* d_out, int out_size, void* d_ws, size_t ws_size,
                              hipStream_t stream) {
    const float* x    = (const float*)d_in[0];
    const float* W1   = (const float*)d_in[2];
    const float* b1   = (const float*)d_in[3];
    const float* g1   = (const float*)d_in[4];
    const float* be1  = (const float*)d_in[5];
    const float* W2   = (const float*)d_in[6];
    const float* b2   = (const float*)d_in[7];
    const float* g2   = (const float*)d_in[8];
    const float* be2  = (const float*)d_in[9];
    const float* Wres = (const float*)d_in[10];
    const float* bres = (const float*)d_in[11];
    float* out = (float*)d_out;

    char* ws = (char*)d_ws;
    float* sqn           = (float*)(ws);                     // 131072 B
    unsigned short* wa   = (unsigned short*)(ws + 131072);   // 16384 B
    unsigned short* wb   = (unsigned short*)(ws + 147456);   // 16384 B
    unsigned short* wrt  = (unsigned short*)(ws + 163840);   // 16384 B
    unsigned short* w2p  = (unsigned short*)(ws + 180224);   // 32768 B
    int* knn_idx         = (int*)(ws + 212992);              // 2621440 B
    unsigned short* Yb   = (unsigned short*)(ws + 2834432);  // 8388608 B -> end 11223040

    unsigned short* xhi = (unsigned short*)d_out;                       // 4 MB
    unsigned short* xlo = (unsigned short*)((char*)d_out + 4194304);    // 4 MB

    k_prep  <<<dim3(1024),      dim3(256), 0, stream>>>(x, xhi, xlo, sqn);
    k_wt    <<<dim3(160),       dim3(256), 0, stream>>>(W1, W2, Wres, wa, wb, wrt, w2p);
    k_knn   <<<dim3(NB * 128),  dim3(512), 0, stream>>>(x, xhi, xlo, sqn, knn_idx);
    k_ybres <<<dim3(NTOT / 64), dim3(256), 0, stream>>>(xhi, wb, wrt, bres, Yb, out);
    k_edge  <<<dim3(NEDGE / 160), dim3(320), 0, stream>>>(x, knn_idx, Yb, w2p, wa,
                                                          b1, g1, be1, b2, g2, be2, out);
}

// Round 14
// 396.018 us; speedup vs baseline: 1.0743x; 1.0743x over previous
//
#include <hip/hip_runtime.h>
#include <hip/hip_bf16.h>

// EdgeConv block: B=8 clouds, N=4096 pts, K=20 nn, C_IN=64, C_OUT=128.
// Key identity: e@W1 = [xi | xj-xi]@W1 = xi@Wa + xj@Wb  (Wa=W1top-W1bot, Wb=W1bot)
// Pipeline: k_prep (x -> bf16 hi/lo planes + sqn=-0.5*|x|^2) -> k_wt
//   -> k_knn (R12 structure; candidate hi-plane only (R13-validated), RB=28)
//   -> k_ybres (Yb = x@Wb bf16; out = x@Wres + bres, one kernel)
//   -> k_edge (Ya in-block MFMA; v=Ya[p]+Yb[j]; LN1; GEMM2(W2 LDS packed); LN2; max; add)

#define NB 8
#define NPTS 4096
#define KNN 20
#define NTOT (NB * NPTS)       // 32768
#define NEDGE (NTOT * KNN)     // 655360
#define LDA 136                // bf16 row stride (128 + 8 pad) -> 272 B
#define RB 28                  // recheck buffer size

typedef short bf16x8 __attribute__((ext_vector_type(8)));
typedef float f32x4 __attribute__((ext_vector_type(4)));

__device__ __forceinline__ unsigned short f2bf(float f) {
    union { float f; unsigned u; } v; v.f = f;
    unsigned r = v.u + 0x7FFFu + ((v.u >> 16) & 1u);   // RTNE
    return (unsigned short)(r >> 16);
}
__device__ __forceinline__ float bf2f(unsigned short s) {
    union { unsigned u; float f; } v; v.u = ((unsigned)s) << 16;
    return v.f;
}

// ---------------- x -> bf16 hi/lo planes + sqn = -0.5*rowsum(x^2) ----------------
__global__ __launch_bounds__(256) void k_prep(const float* __restrict__ x,
                                              unsigned short* __restrict__ xhi,
                                              unsigned short* __restrict__ xlo,
                                              float* __restrict__ sqn) {
    int id = blockIdx.x * 2048 + threadIdx.x * 8;
    float4 v0 = *(const float4*)(x + id);
    float4 v1 = *(const float4*)(x + id + 4);
    float vs[8] = {v0.x, v0.y, v0.z, v0.w, v1.x, v1.y, v1.z, v1.w};
    unsigned short h[8], l[8];
    float s = 0.f;
#pragma unroll
    for (int i = 0; i < 8; ++i) {
        h[i] = f2bf(vs[i]);
        l[i] = f2bf(vs[i] - bf2f(h[i]));
        s += vs[i] * vs[i];
    }
    uint4 hp, lp;
    hp.x = h[0] | ((unsigned)h[1] << 16); hp.y = h[2] | ((unsigned)h[3] << 16);
    hp.z = h[4] | ((unsigned)h[5] << 16); hp.w = h[6] | ((unsigned)h[7] << 16);
    lp.x = l[0] | ((unsigned)l[1] << 16); lp.y = l[2] | ((unsigned)l[3] << 16);
    lp.z = l[4] | ((unsigned)l[5] << 16); lp.w = l[6] | ((unsigned)l[7] << 16);
    *(uint4*)(xhi + id) = hp;
    *(uint4*)(xlo + id) = lp;
    s += __shfl_xor(s, 1); s += __shfl_xor(s, 2); s += __shfl_xor(s, 4);
    if ((threadIdx.x & 7) == 0) sqn[id >> 6] = -0.5f * s;
}

// ---------------- weights: Wa/Wb/Wres transposed bf16 + W2 frag-packed ----------------
__global__ __launch_bounds__(256) void k_wt(const float* __restrict__ W1, const float* __restrict__ W2,
                                            const float* __restrict__ Wres,
                                            unsigned short* __restrict__ wa, unsigned short* __restrict__ wb,
                                            unsigned short* __restrict__ wrt, unsigned short* __restrict__ w2p) {
    int id = blockIdx.x * 256 + threadIdx.x;   // 0..40959
    if (id < 16384) {
        int f = id >> 9, pos = id & 511;
        int lane = pos >> 3, m = pos & 7;
        int ks = f >> 3, nt = f & 7;
        int lr = lane & 15, kg = lane >> 4;
        int c = ks * 32 + kg * 8 + m;
        int d = nt * 16 + lr;
        w2p[id] = f2bf(W2[c * 128 + d]);
    } else if (id < 24576) {
        int i = id - 16384;
        int d = i >> 6, c = i & 63;
        wa[i] = f2bf(W1[c * 128 + d] - W1[(64 + c) * 128 + d]);
    } else if (id < 32768) {
        int i = id - 24576;
        int d = i >> 6, c = i & 63;
        wb[i] = f2bf(W1[(64 + c) * 128 + d]);
    } else {
        int i = id - 32768;
        int d = i >> 6, c = i & 63;
        wrt[i] = f2bf(Wres[c * 128 + d]);
    }
}

// ---------------- KNN via MFMA, 8-wave single-pass, hi-only candidates ----------------
// Waves: (qgrp = w>>1) x (tp = w&1). Super s covers tiles 2s+tp (32 cands each).
// score = -0.5|c|^2 + chi.(qhi+qlo)  (drops clo terms; error ~0.02 << rank spacing,
// absorbed by RB=28 exact-fp32 recheck buffer -- validated in R13, identical absmax).
// Staging: wave w stages ONE 1KB frag (st=w>>2, kh=(w>>1)&1) of tile tp per super.
// Lane (lr=query, kg) streams 512 cands: packed (score|idx12) med3 top-20.
__global__ __launch_bounds__(512, 4) void k_knn(const float* __restrict__ x,
                                                const unsigned short* __restrict__ xhi,
                                                const unsigned short* __restrict__ xlo,
                                                const float* __restrict__ sqn,
                                                int* __restrict__ knn_idx) {
    int b  = blockIdx.x & 7;           // cloud -> XCD pinning
    int qb = blockIdx.x >> 3;          // 0..63
    int t  = threadIdx.x;
    int w = t >> 6, lane = t & 63;
    int lr = lane & 15, kg = lane >> 4;
    int qgrp = w >> 1, tp = w & 1;
    int n0  = b * NPTS + qb * 64;
    int cb0 = b * NPTS;

    // LDS liveness union (48384 B -> 3 blocks/CU):
    //   stream: ring 16384 B; merge: md 41216 + ci 7168 (disjoint); recheck: ce overlays md
    __shared__ union {
        unsigned short ring[2][2][4][512];                 // [buf][tp][frag=st*2+kh][shorts]
        struct { float md[64][161]; int ci[64][RB]; } m;
        struct { float ce[64][RB]; } r;
    } U;

    // query B-fragments (col = lane&15, k-slice kg*8), hi/lo x 2 K-halves
    int qg = n0 + qgrp * 16 + lr;
    bf16x8 qhi0 = *(const bf16x8*)(xhi + (size_t)qg * 64 + kg * 8);
    bf16x8 qhi1 = *(const bf16x8*)(xhi + (size_t)qg * 64 + 32 + kg * 8);
    bf16x8 qlo0 = *(const bf16x8*)(xlo + (size_t)qg * 64 + kg * 8);
    bf16x8 qlo1 = *(const bf16x8*)(xlo + (size_t)qg * 64 + 32 + kg * 8);

    // staging role: wave w stages frag f = st*2+kh of tile tp (hi plane only)
    int sst = w >> 2, skh = (w >> 1) & 1;
    int sfrag = sst * 2 + skh;
    size_t soff = (size_t)(sst * 16 + lr) * 64 + skh * 32 + kg * 8;

    float kd[KNN];
#pragma unroll
    for (int p = 0; p < KNN; ++p) kd[p] = 3.4e38f;
    int myq = qgrp * 16 + lr;

    // prologue: stage super 0 (tile tp); prefetch super 1
    {
        uint4 p0 = *(const uint4*)(xhi + (size_t)(cb0 + tp * 32) * 64 + soff);
        *(uint4*)&U.ring[0][tp][sfrag][lane * 8] = p0;
    }
    uint4 g0 = *(const uint4*)(xhi + (size_t)(cb0 + (2 + tp) * 32) * 64 + soff);
    float4 sqc0 = *(const float4*)&sqn[cb0 + tp * 32 + kg * 4];
    float4 sqc1 = *(const float4*)&sqn[cb0 + tp * 32 + 16 + kg * 4];
    __syncthreads();

#pragma unroll 1
    for (int s = 0; s < 64; ++s) {
        if (s + 1 < 64) {                      // publish prefetched super s+1
            *(uint4*)&U.ring[(s + 1) & 1][tp][sfrag][lane * 8] = g0;
        }
        if (s + 2 < 64) {                      // issue loads for super s+2
            g0 = *(const uint4*)(xhi + (size_t)(cb0 + (2 * (s + 2) + tp) * 32) * 64 + soff);
        }
        float4 nsq0, nsq1;
        if (s + 1 < 64) {                      // prefetch next sqn
            nsq0 = *(const float4*)&sqn[cb0 + (2 * (s + 1) + tp) * 32 + kg * 4];
            nsq1 = *(const float4*)&sqn[cb0 + (2 * (s + 1) + tp) * 32 + 16 + kg * 4];
        }

        const unsigned short* fr = &U.ring[s & 1][tp][0][0];
        bf16x8 A0 = *(const bf16x8*)(fr + 0 * 512 + lane * 8);   // st0 kh0
        bf16x8 A1 = *(const bf16x8*)(fr + 1 * 512 + lane * 8);   // st0 kh1
        bf16x8 A2 = *(const bf16x8*)(fr + 2 * 512 + lane * 8);   // st1 kh0
        bf16x8 A3 = *(const bf16x8*)(fr + 3 * 512 + lane * 8);   // st1 kh1

        // C-init = sqn (pre-scaled -0.5*sq, prefetched): register copy
        f32x4 a00 = {sqc0.x, sqc0.y, sqc0.z, sqc0.w};
        f32x4 a01 = {0.f, 0.f, 0.f, 0.f};
        f32x4 a10 = {sqc1.x, sqc1.y, sqc1.z, sqc1.w};
        f32x4 a11 = {0.f, 0.f, 0.f, 0.f};
        // dot = chi.(qhi+qlo): 8 MFMAs, 4 independent chains of 2
        a00 = __builtin_amdgcn_mfma_f32_16x16x32_bf16(A0, qhi0, a00, 0, 0, 0);
        a10 = __builtin_amdgcn_mfma_f32_16x16x32_bf16(A2, qhi0, a10, 0, 0, 0);
        a01 = __builtin_amdgcn_mfma_f32_16x16x32_bf16(A1, qhi1, a01, 0, 0, 0);
        a11 = __builtin_amdgcn_mfma_f32_16x16x32_bf16(A3, qhi1, a11, 0, 0, 0);
        a00 = __builtin_amdgcn_mfma_f32_16x16x32_bf16(A0, qlo0, a00, 0, 0, 0);
        a10 = __builtin_amdgcn_mfma_f32_16x16x32_bf16(A2, qlo0, a10, 0, 0, 0);
        a01 = __builtin_amdgcn_mfma_f32_16x16x32_bf16(A1, qlo1, a01, 0, 0, 0);
        a11 = __builtin_amdgcn_mfma_f32_16x16x32_bf16(A3, qlo1, a11, 0, 0, 0);

        int ibase = (2 * s + tp) * 32 + kg * 4;
#pragma unroll
        for (int j = 0; j < 8; ++j) {
            float sc = (j < 4) ? -(a00[j & 3] + a01[j & 3]) : -(a10[j & 3] + a11[j & 3]);
            unsigned idx12 = (unsigned)(ibase + ((j >> 2) << 4) + (j & 3));
            float xv = __uint_as_float((__float_as_uint(sc) & 0xFFFFF000u) | idx12);
#pragma unroll
            for (int p = KNN - 1; p >= 1; --p)
                kd[p] = __builtin_amdgcn_fmed3f(xv, kd[p - 1], kd[p]);
            kd[0] = fminf(kd[0], xv);
        }

        __syncthreads();
        sqc0 = nsq0; sqc1 = nsq1;
    }

    __syncthreads();   // ring dead; union repurposed as md/ci
#pragma unroll
    for (int p = 0; p < KNN; ++p) U.m.md[myq][(tp * 4 + kg) * KNN + p] = kd[p];
    __syncthreads();

    // merge 8 sorted lists -> top-RB packed (t<64)
    if (t < 64) {
        float kdm[RB];
#pragma unroll
        for (int s2 = 0; s2 < RB; ++s2) kdm[s2] = 3.4e38f;
        float km = 3.4e38f;
#pragma unroll 1
        for (int u = 0; u < 8; ++u) {
#pragma unroll 1
            for (int p = 0; p < KNN; ++p) {
                float d = U.m.md[t][u * KNN + p];
                if (d >= km) break;            // ascending list: rest can't qualify
#pragma unroll
                for (int s2 = RB - 1; s2 >= 1; --s2)
                    kdm[s2] = __builtin_amdgcn_fmed3f(d, kdm[s2 - 1], kdm[s2]);
                kdm[0] = fminf(kdm[0], d);
                km = kdm[RB - 1];
            }
        }
#pragma unroll
        for (int s2 = 0; s2 < RB; ++s2)
            U.m.ci[t][s2] = (int)(__float_as_uint(kdm[s2]) & 0xFFFu) + cb0;
    }
    __syncthreads();   // md dead; ce overlays it (ci persists at disjoint offset)

    // exact fp32 recheck: 64*RB = 1792 tasks over 512 threads (rows L1/L2-hot)
#pragma unroll 1
    for (int task = t; task < 64 * RB; task += 512) {
        int q = task / RB, sl = task - q * RB;
        int cidx = U.m.ci[q][sl];
        const float* xqp = x + (size_t)(n0 + q) * 64;
        const float* xc  = x + (size_t)cidx * 64;
        float dot = 0.f;
#pragma unroll
        for (int g = 0; g < 16; ++g) {
            float4 a = *(const float4*)(xqp + g * 4);
            float4 bb = *(const float4*)(xc + g * 4);
            dot += a.x * bb.x + a.y * bb.y + a.z * bb.z + a.w * bb.w;
        }
        U.r.ce[q][sl] = -sqn[cidx] - dot;     // = 0.5*sq - dot
    }
    __syncthreads();

    // drop the RB-KNN lexicographically-largest (score, then higher idx) -> exact top-20 set
    if (t < 64) {
        float ev[RB]; int iv[RB];
#pragma unroll
        for (int s2 = 0; s2 < RB; ++s2) { ev[s2] = U.r.ce[t][s2]; iv[s2] = U.m.ci[t][s2]; }
        unsigned mask = 0;
#pragma unroll
        for (int pass = 0; pass < RB - KNN; ++pass) {
            float best = -3.4e38f; int bid = -1, bs = 0;
#pragma unroll
            for (int s2 = 0; s2 < RB; ++s2) {
                bool free_ = ((mask >> s2) & 1u) == 0u;
                bool gt = (ev[s2] > best) || (ev[s2] == best && iv[s2] > bid);
                if (free_ && gt) { best = ev[s2]; bid = iv[s2]; bs = s2; }
            }
            mask |= 1u << bs;
        }
        int* op = knn_idx + (size_t)(n0 + t) * KNN;
        int pos = 0;
#pragma unroll
        for (int s2 = 0; s2 < RB; ++s2)
            if (((mask >> s2) & 1u) == 0u) op[pos++] = iv[s2];
    }
}

// ---------------- fused Yb = x@Wb (bf16) and out = x@Wres + bres ----------------
__global__ __launch_bounds__(256) void k_ybres(const unsigned short* __restrict__ xhi,
                                               const unsigned short* __restrict__ wb,
                                               const unsigned short* __restrict__ wrt,
                                               const float* __restrict__ bres,
                                               unsigned short* __restrict__ Yb,
                                               float* __restrict__ out) {
    int t = threadIdx.x;
    int wv = t >> 6, lane = t & 63;
    int lr = lane & 15, kg = lane >> 4;
    int n0 = blockIdx.x * 64 + wv * 16;

    bf16x8 af0 = *(const bf16x8*)(xhi + (size_t)(n0 + lr) * 64 + kg * 8);
    bf16x8 af1 = *(const bf16x8*)(xhi + (size_t)(n0 + lr) * 64 + 32 + kg * 8);

    f32x4 accY[8], accR[8];
#pragma unroll
    for (int nt = 0; nt < 8; ++nt) {
        accY[nt] = (f32x4){0.f, 0.f, 0.f, 0.f};
        float bv = bres[nt * 16 + lr];
        accR[nt] = (f32x4){bv, bv, bv, bv};
    }
#pragma unroll
    for (int nt = 0; nt < 8; ++nt) {
        bf16x8 b0 = *(const bf16x8*)(wb + (size_t)(nt * 16 + lr) * 64 + kg * 8);
        bf16x8 b1 = *(const bf16x8*)(wb + (size_t)(nt * 16 + lr) * 64 + 32 + kg * 8);
        accY[nt] = __builtin_amdgcn_mfma_f32_16x16x32_bf16(af0, b0, accY[nt], 0, 0, 0);
        accY[nt] = __builtin_amdgcn_mfma_f32_16x16x32_bf16(af1, b1, accY[nt], 0, 0, 0);
        bf16x8 r0 = *(const bf16x8*)(wrt + (size_t)(nt * 16 + lr) * 64 + kg * 8);
        bf16x8 r1 = *(const bf16x8*)(wrt + (size_t)(nt * 16 + lr) * 64 + 32 + kg * 8);
        accR[nt] = __builtin_amdgcn_mfma_f32_16x16x32_bf16(af0, r0, accR[nt], 0, 0, 0);
        accR[nt] = __builtin_amdgcn_mfma_f32_16x16x32_bf16(af1, r1, accR[nt], 0, 0, 0);
    }
#pragma unroll
    for (int nt = 0; nt < 8; ++nt)
#pragma unroll
        for (int j = 0; j < 4; ++j) {
            Yb[(size_t)(n0 + kg * 4 + j) * 128 + nt * 16 + lr] = f2bf(accY[nt][j]);
            out[(size_t)(n0 + kg * 4 + j) * 128 + nt * 16 + lr] = accR[nt][j];
        }
}

// ---------------- LN2 helper (C-frag layout; wave-local rows) ----------------
__device__ __forceinline__ void ln_relu_store(f32x4 acc[2][8], unsigned short* A, int wv, int lane,
                                              const float* __restrict__ bias, const float* __restrict__ g,
                                              const float* __restrict__ be) {
    int lc = lane & 15, kg = lane >> 4;
    float bv[8], gv[8], bev[8];
#pragma unroll
    for (int nt = 0; nt < 8; ++nt) {
        bv[nt]  = bias[nt * 16 + lc];
        gv[nt]  = g[nt * 16 + lc];
        bev[nt] = be[nt * 16 + lc];
    }
#pragma unroll
    for (int mt = 0; mt < 2; ++mt) {
#pragma unroll
        for (int j = 0; j < 4; ++j) {
            float v[8]; float s = 0.f, ss = 0.f;
#pragma unroll
            for (int nt = 0; nt < 8; ++nt) {
                v[nt] = acc[mt][nt][j] + bv[nt];
                s += v[nt]; ss += v[nt] * v[nt];
            }
#pragma unroll
            for (int m = 1; m < 16; m <<= 1) { s += __shfl_xor(s, m); ss += __shfl_xor(ss, m); }
            float mean = s * 0.0078125f;
            float var  = ss * 0.0078125f - mean * mean;
            float rstd = rsqrtf(fmaxf(var, 0.f) + 1e-5f);
            int row = wv * 32 + mt * 16 + kg * 4 + j;
#pragma unroll
            for (int nt = 0; nt < 8; ++nt) {
                float h = (v[nt] - mean) * rstd * gv[nt] + bev[nt];
                h = fmaxf(h, 0.f);
                A[(size_t)row * LDA + nt * 16 + lc] = f2bf(h);
            }
        }
    }
}

// ---------------- fused edge kernel (no GEMM1) ----------------
__global__ __launch_bounds__(320, 2) void k_edge(const float* __restrict__ x, const int* __restrict__ knn_idx,
                                                 const unsigned short* __restrict__ Yb,
                                                 const unsigned short* __restrict__ w2p,
                                                 const unsigned short* __restrict__ wa,
                                                 const float* __restrict__ b1, const float* __restrict__ g1, const float* __restrict__ be1,
                                                 const float* __restrict__ b2, const float* __restrict__ g2, const float* __restrict__ be2,
                                                 float* __restrict__ out) {
    __shared__ unsigned short A[160 * LDA];    // 43520 B: h1 -> h2
    __shared__ unsigned short W2s[32 * 512];   // 32768 B: W2 frag-packed
    __shared__ float Ya8[8][128];              // 4096 B
    __shared__ float GB[256];                  // g1 | be1
    int t = threadIdx.x;
    int bid = blockIdx.x;
    int blk = (bid & 7) * 512 + (bid >> 3);    // XCD swizzle: cloud-pinned

    for (int id = t; id < 2048; id += 320)
        *(uint4*)&W2s[id * 8] = *(const uint4*)(w2p + (size_t)id * 8);
    if (t < 32)       *(float4*)&GB[t * 4] = *(const float4*)(g1 + t * 4);
    else if (t < 64)  *(float4*)&GB[t * 4] = *(const float4*)(be1 + (t - 32) * 4);

    int r = t >> 1, h = t & 1;
    int eg = blk * 160 + r;
    int ploc = r / 20;
    int jn = knn_idx[eg];
    uint4 ybr[8];
    {
        const unsigned short* ybp = Yb + (size_t)jn * 128 + h * 64;
#pragma unroll
        for (int i = 0; i < 8; ++i) ybr[i] = *(const uint4*)(ybp + i * 8);
    }

    if (t < 64) {
        int lane = t, lr = lane & 15, kg = lane >> 4;
        int prow = blk * 8 + (lr & 7);
        const float* xp = x + (size_t)prow * 64;
        bf16x8 af0, af1;
        {
            union { unsigned short u[8]; bf16x8 v; } cv;
            float4 u0 = *(const float4*)(xp + kg * 8);
            float4 u1 = *(const float4*)(xp + kg * 8 + 4);
            cv.u[0] = f2bf(u0.x); cv.u[1] = f2bf(u0.y); cv.u[2] = f2bf(u0.z); cv.u[3] = f2bf(u0.w);
            cv.u[4] = f2bf(u1.x); cv.u[5] = f2bf(u1.y); cv.u[6] = f2bf(u1.z); cv.u[7] = f2bf(u1.w);
            af0 = cv.v;
            float4 w0 = *(const float4*)(xp + 32 + kg * 8);
            float4 w1 = *(const float4*)(xp + 32 + kg * 8 + 4);
            cv.u[0] = f2bf(w0.x); cv.u[1] = f2bf(w0.y); cv.u[2] = f2bf(w0.z); cv.u[3] = f2bf(w0.w);
            cv.u[4] = f2bf(w1.x); cv.u[5] = f2bf(w1.y); cv.u[6] = f2bf(w1.z); cv.u[7] = f2bf(w1.w);
            af1 = cv.v;
        }
        f32x4 accA[8];
#pragma unroll
        for (int nt = 0; nt < 8; ++nt) {
            float bv = b1[nt * 16 + lr];
            accA[nt] = (f32x4){bv, bv, bv, bv};
        }
#pragma unroll
        for (int nt = 0; nt < 8; ++nt) {
            bf16x8 b0 = *(const bf16x8*)(wa + (size_t)(nt * 16 + lr) * 64 + kg * 8);
            bf16x8 b1f = *(const bf16x8*)(wa + (size_t)(nt * 16 + lr) * 64 + 32 + kg * 8);
            accA[nt] = __builtin_amdgcn_mfma_f32_16x16x32_bf16(af0, b0, accA[nt], 0, 0, 0);
            accA[nt] = __builtin_amdgcn_mfma_f32_16x16x32_bf16(af1, b1f, accA[nt], 0, 0, 0);
        }
#pragma unroll
        for (int nt = 0; nt < 8; ++nt)
#pragma unroll
            for (int j = 0; j < 4; ++j) {
                int rr = kg * 4 + j;
                if (rr < 8) Ya8[rr][nt * 16 + lr] = accA[nt][j];
            }
    }
    __syncthreads();

    {
        float v[64]; float s = 0.f, ss = 0.f;
#pragma unroll
        for (int i = 0; i < 8; ++i) {
            unsigned uu[4] = {ybr[i].x, ybr[i].y, ybr[i].z, ybr[i].w};
#pragma unroll
            for (int k2 = 0; k2 < 4; ++k2) {
                int c = h * 64 + i * 8 + 2 * k2;
                float w0 = Ya8[ploc][c]     + bf2f((unsigned short)(uu[k2] & 0xFFFFu));
                float w1 = Ya8[ploc][c + 1] + bf2f((unsigned short)(uu[k2] >> 16));
                v[i * 8 + 2 * k2] = w0; v[i * 8 + 2 * k2 + 1] = w1;
                s += w0 + w1; ss += w0 * w0 + w1 * w1;
            }
        }
        s += __shfl_xor(s, 1); ss += __shfl_xor(ss, 1);
        float mean = s * 0.0078125f;
        float var  = ss * 0.0078125f - mean * mean;
        float rstd = rsqrtf(fmaxf(var, 0.f) + 1e-5f);
#pragma unroll
        for (int i = 0; i < 8; ++i) {
            unsigned short hh[8];
#pragma unroll
            for (int k2 = 0; k2 < 8; ++k2) {
                int c = h * 64 + i * 8 + k2;
                float hv = (v[i * 8 + k2] - mean) * rstd * GB[c] + GB[128 + c];
                hh[k2] = f2bf(fmaxf(hv, 0.f));
            }
            uint4 pk;
            pk.x = hh[0] | ((unsigned)hh[1] << 16); pk.y = hh[2] | ((unsigned)hh[3] << 16);
            pk.z = hh[4] | ((unsigned)hh[5] << 16); pk.w = hh[6] | ((unsigned)hh[7] << 16);
            *(uint4*)&A[(size_t)r * LDA + h * 64 + i * 8] = pk;
        }
    }

    int wv = t >> 6, lane = t & 63;
    int lr = lane & 15, kg = lane >> 4;
    f32x4 acc2[2][8];
#pragma unroll
    for (int i = 0; i < 2; ++i)
#pragma unroll
        for (int j = 0; j < 8; ++j) acc2[i][j] = (f32x4){0.f, 0.f, 0.f, 0.f};
#pragma unroll
    for (int ks = 0; ks < 4; ++ks) {
        int ko = ks * 32 + kg * 8;
        bf16x8 a0 = *(const bf16x8*)(A + (size_t)(wv * 32 + lr) * LDA + ko);
        bf16x8 a1 = *(const bf16x8*)(A + (size_t)(wv * 32 + 16 + lr) * LDA + ko);
#pragma unroll
        for (int nt = 0; nt < 8; ++nt) {
            bf16x8 bf = *(const bf16x8*)&W2s[(size_t)(ks * 8 + nt) * 512 + lane * 8];
            acc2[0][nt] = __builtin_amdgcn_mfma_f32_16x16x32_bf16(a0, bf, acc2[0][nt], 0, 0, 0);
            acc2[1][nt] = __builtin_amdgcn_mfma_f32_16x16x32_bf16(a1, bf, acc2[1][nt], 0, 0, 0);
        }
    }
    ln_relu_store(acc2, A, wv, lane, b2, g2, be2);

    __syncthreads();

    if (t < 128) {
        int p = t >> 4, cg = t & 15;
        int n = blk * 8 + p;
        float mx[8];
#pragma unroll
        for (int k = 0; k < 8; ++k) mx[k] = 0.f;
#pragma unroll
        for (int rr = 0; rr < 20; ++rr) {
            uint4 vv = *(const uint4*)&A[(size_t)(p * 20 + rr) * LDA + cg * 8];
            unsigned uu[4] = {vv.x, vv.y, vv.z, vv.w};
#pragma unroll
            for (int k = 0; k < 4; ++k) {
                float lo = __uint_as_float(uu[k] << 16);
                float hi = __uint_as_float(uu[k] & 0xFFFF0000u);
                mx[2 * k]     = fmaxf(mx[2 * k], lo);
                mx[2 * k + 1] = fmaxf(mx[2 * k + 1], hi);
            }
        }
        float* op = out + (size_t)n * 128 + cg * 8;
        float4 o0 = *(float4*)op;
        float4 o1 = *(float4*)(op + 4);
        o0.x += mx[0]; o0.y += mx[1]; o0.z += mx[2]; o0.w += mx[3];
        o1.x += mx[4]; o1.y += mx[5]; o1.z += mx[6]; o1.w += mx[7];
        *(float4*)op = o0;
        *(float4*)(op + 4) = o1;
    }
}

// ---------------- launcher ----------------
extern "C" void kernel_launch(void* const* d_in, const int* in_sizes, int n_in,
                              void* d_out, int out_size, void* d_ws, size_t ws_size,
                              hipStream_t stream) {
    const float* x    = (const float*)d_in[0];
    const float* W1   = (const float*)d_in[2];
    const float* b1   = (const float*)d_in[3];
    const float* g1   = (const float*)d_in[4];
    const float* be1  = (const float*)d_in[5];
    const float* W2   = (const float*)d_in[6];
    const float* b2   = (const float*)d_in[7];
    const float* g2   = (const float*)d_in[8];
    const float* be2  = (const float*)d_in[9];
    const float* Wres = (const float*)d_in[10];
    const float* bres = (const float*)d_in[11];
    float* out = (float*)d_out;

    char* ws = (char*)d_ws;
    float* sqn           = (float*)(ws);                     // 131072 B
    unsigned short* wa   = (unsigned short*)(ws + 131072);   // 16384 B
    unsigned short* wb   = (unsigned short*)(ws + 147456);   // 16384 B
    unsigned short* wrt  = (unsigned short*)(ws + 163840);   // 16384 B
    unsigned short* w2p  = (unsigned short*)(ws + 180224);   // 32768 B
    int* knn_idx         = (int*)(ws + 212992);              // 2621440 B
    unsigned short* Yb   = (unsigned short*)(ws + 2834432);  // 8388608 B -> end 11223040

    unsigned short* xhi = (unsigned short*)d_out;                       // 4 MB
    unsigned short* xlo = (unsigned short*)((char*)d_out + 4194304);    // 4 MB

    k_prep  <<<dim3(1024),      dim3(256), 0, stream>>>(x, xhi, xlo, sqn);
    k_wt    <<<dim3(160),       dim3(256), 0, stream>>>(W1, W2, Wres, wa, wb, wrt, w2p);
    k_knn   <<<dim3(NB * 64),   dim3(512), 0, stream>>>(x, xhi, xlo, sqn, knn_idx);
    k_ybres <<<dim3(NTOT / 64), dim3(256), 0, stream>>>(xhi, wb, wrt, bres, Yb, out);
    k_edge  <<<dim3(NEDGE / 160), dim3(320), 0, stream>>>(x, knn_idx, Yb, w2p, wa,
                                                          b1, g1, be1, b2, g2, be2, out);
}

// Round 15
// 381.626 us; speedup vs baseline: 1.1148x; 1.0377x over previous
//
#include <hip/hip_runtime.h>
#include <hip/hip_bf16.h>

// EdgeConv block: B=8 clouds, N=4096 pts, K=20 nn, C_IN=64, C_OUT=128.
// Key identity: e@W1 = [xi | xj-xi]@W1 = xi@Wa + xj@Wb  (Wa=W1top-W1bot, Wb=W1bot)
// Pipeline: k_prep (x -> bf16 hi/lo planes + sqn=-0.5*|x|^2) -> k_wt
//   -> k_knn (hi-only candidates, RB=28, TWO supers per barrier: 32 barriers)
//   -> k_ybres (Yb = x@Wb bf16; out = x@Wres + bres, one kernel)
//   -> k_edge (Ya in-block MFMA; v=Ya[p]+Yb[j]; LN1; GEMM2(W2 LDS packed); LN2; max; add)

#define NB 8
#define NPTS 4096
#define KNN 20
#define NTOT (NB * NPTS)       // 32768
#define NEDGE (NTOT * KNN)     // 655360
#define LDA 136                // bf16 row stride (128 + 8 pad) -> 272 B
#define RB 28                  // recheck buffer size

typedef short bf16x8 __attribute__((ext_vector_type(8)));
typedef float f32x4 __attribute__((ext_vector_type(4)));

__device__ __forceinline__ unsigned short f2bf(float f) {
    union { float f; unsigned u; } v; v.f = f;
    unsigned r = v.u + 0x7FFFu + ((v.u >> 16) & 1u);   // RTNE
    return (unsigned short)(r >> 16);
}
__device__ __forceinline__ float bf2f(unsigned short s) {
    union { unsigned u; float f; } v; v.u = ((unsigned)s) << 16;
    return v.f;
}

// ---------------- x -> bf16 hi/lo planes + sqn = -0.5*rowsum(x^2) ----------------
__global__ __launch_bounds__(256) void k_prep(const float* __restrict__ x,
                                              unsigned short* __restrict__ xhi,
                                              unsigned short* __restrict__ xlo,
                                              float* __restrict__ sqn) {
    int id = blockIdx.x * 2048 + threadIdx.x * 8;
    float4 v0 = *(const float4*)(x + id);
    float4 v1 = *(const float4*)(x + id + 4);
    float vs[8] = {v0.x, v0.y, v0.z, v0.w, v1.x, v1.y, v1.z, v1.w};
    unsigned short h[8], l[8];
    float s = 0.f;
#pragma unroll
    for (int i = 0; i < 8; ++i) {
        h[i] = f2bf(vs[i]);
        l[i] = f2bf(vs[i] - bf2f(h[i]));
        s += vs[i] * vs[i];
    }
    uint4 hp, lp;
    hp.x = h[0] | ((unsigned)h[1] << 16); hp.y = h[2] | ((unsigned)h[3] << 16);
    hp.z = h[4] | ((unsigned)h[5] << 16); hp.w = h[6] | ((unsigned)h[7] << 16);
    lp.x = l[0] | ((unsigned)l[1] << 16); lp.y = l[2] | ((unsigned)l[3] << 16);
    lp.z = l[4] | ((unsigned)l[5] << 16); lp.w = l[6] | ((unsigned)l[7] << 16);
    *(uint4*)(xhi + id) = hp;
    *(uint4*)(xlo + id) = lp;
    s += __shfl_xor(s, 1); s += __shfl_xor(s, 2); s += __shfl_xor(s, 4);
    if ((threadIdx.x & 7) == 0) sqn[id >> 6] = -0.5f * s;
}

// ---------------- weights: Wa/Wb/Wres transposed bf16 + W2 frag-packed ----------------
__global__ __launch_bounds__(256) void k_wt(const float* __restrict__ W1, const float* __restrict__ W2,
                                            const float* __restrict__ Wres,
                                            unsigned short* __restrict__ wa, unsigned short* __restrict__ wb,
                                            unsigned short* __restrict__ wrt, unsigned short* __restrict__ w2p) {
    int id = blockIdx.x * 256 + threadIdx.x;   // 0..40959
    if (id < 16384) {
        int f = id >> 9, pos = id & 511;
        int lane = pos >> 3, m = pos & 7;
        int ks = f >> 3, nt = f & 7;
        int lr = lane & 15, kg = lane >> 4;
        int c = ks * 32 + kg * 8 + m;
        int d = nt * 16 + lr;
        w2p[id] = f2bf(W2[c * 128 + d]);
    } else if (id < 24576) {
        int i = id - 16384;
        int d = i >> 6, c = i & 63;
        wa[i] = f2bf(W1[c * 128 + d] - W1[(64 + c) * 128 + d]);
    } else if (id < 32768) {
        int i = id - 24576;
        int d = i >> 6, c = i & 63;
        wb[i] = f2bf(W1[(64 + c) * 128 + d]);
    } else {
        int i = id - 32768;
        int d = i >> 6, c = i & 63;
        wrt[i] = f2bf(Wres[c * 128 + d]);
    }
}

// ---------------- KNN via MFMA: hi-only candidates, 2 supers per barrier ----------------
// Waves: (qgrp = w>>1) x (tp = w&1). Iter i covers supers {2i, 2i+1}; super S covers
// tile 2S+tp (32 cands). 32 iters, ONE barrier each (vs 64 in R12/R14).
// score = -0.5|c|^2 + chi.(qhi+qlo)  (hi-only cands; error ~0.02 absorbed by RB=28
// exact-fp32 recheck -- validated R13/R14, identical absmax).
// Staging: wave w stages frag sfrag=sst*2+skh of tile tp for BOTH supers (2 uint4/iter),
// 2-iter register prefetch. Lane (lr=query, kg) streams 16 cands/iter.
__global__ __launch_bounds__(512, 4) void k_knn(const float* __restrict__ x,
                                                const unsigned short* __restrict__ xhi,
                                                const unsigned short* __restrict__ xlo,
                                                const float* __restrict__ sqn,
                                                int* __restrict__ knn_idx) {
    int b  = blockIdx.x & 7;           // cloud -> XCD pinning
    int qb = blockIdx.x >> 3;          // 0..63
    int t  = threadIdx.x;
    int w = t >> 6, lane = t & 63;
    int lr = lane & 15, kg = lane >> 4;
    int qgrp = w >> 1, tp = w & 1;
    int n0  = b * NPTS + qb * 64;
    int cb0 = b * NPTS;

    // LDS liveness union (48384 B -> fits 3 blocks/CU):
    //   stream: ring 32768 B (2 slots x 2 superhalves x 2 tp x 4 frags x 1KB)
    //   merge:  md 41216 + ci 7168 (disjoint); recheck: ce overlays md
    __shared__ union {
        unsigned short ring[2][2][2][4][512];
        struct { float md[64][161]; int ci[64][RB]; } m;
        struct { float ce[64][RB]; } r;
    } U;

    // query B-fragments (col = lane&15, k-slice kg*8), hi/lo x 2 K-halves
    int qg = n0 + qgrp * 16 + lr;
    bf16x8 qhi0 = *(const bf16x8*)(xhi + (size_t)qg * 64 + kg * 8);
    bf16x8 qhi1 = *(const bf16x8*)(xhi + (size_t)qg * 64 + 32 + kg * 8);
    bf16x8 qlo0 = *(const bf16x8*)(xlo + (size_t)qg * 64 + kg * 8);
    bf16x8 qlo1 = *(const bf16x8*)(xlo + (size_t)qg * 64 + 32 + kg * 8);

    // staging role: wave w stages frag sfrag of tile tp, both supers of each iter
    int sst = w >> 2, skh = (w >> 1) & 1;
    int sfrag = sst * 2 + skh;
    size_t soff = (size_t)(sst * 16 + lr) * 64 + skh * 32 + kg * 8;

    float kd[KNN];
#pragma unroll
    for (int p = 0; p < KNN; ++p) kd[p] = 3.4e38f;
    int myq = qgrp * 16 + lr;

    // prologue: stage iter 0 (tiles tp, 2+tp); prefetch iter 1 (tiles 4+tp, 6+tp)
    {
        uint4 p0 = *(const uint4*)(xhi + (size_t)(cb0 + tp * 32) * 64 + soff);
        uint4 p1 = *(const uint4*)(xhi + (size_t)(cb0 + (2 + tp) * 32) * 64 + soff);
        *(uint4*)&U.ring[0][0][tp][sfrag][lane * 8] = p0;
        *(uint4*)&U.ring[0][1][tp][sfrag][lane * 8] = p1;
    }
    uint4 g0 = *(const uint4*)(xhi + (size_t)(cb0 + (4 + tp) * 32) * 64 + soff);
    uint4 g1 = *(const uint4*)(xhi + (size_t)(cb0 + (6 + tp) * 32) * 64 + soff);
    float4 sqc[4];
#pragma unroll
    for (int sh = 0; sh < 2; ++sh) {
        sqc[sh * 2 + 0] = *(const float4*)&sqn[cb0 + (2 * sh + tp) * 32 + kg * 4];
        sqc[sh * 2 + 1] = *(const float4*)&sqn[cb0 + (2 * sh + tp) * 32 + 16 + kg * 4];
    }
    __syncthreads();

#pragma unroll 1
    for (int i = 0; i < 32; ++i) {
        if (i + 1 < 32) {                      // publish prefetched iter i+1
            *(uint4*)&U.ring[(i + 1) & 1][0][tp][sfrag][lane * 8] = g0;
            *(uint4*)&U.ring[(i + 1) & 1][1][tp][sfrag][lane * 8] = g1;
        }
        if (i + 2 < 32) {                      // issue loads for iter i+2
            g0 = *(const uint4*)(xhi + (size_t)(cb0 + (4 * (i + 2) + tp) * 32) * 64 + soff);
            g1 = *(const uint4*)(xhi + (size_t)(cb0 + (4 * (i + 2) + 2 + tp) * 32) * 64 + soff);
        }
        float4 nsq[4];
        if (i + 1 < 32) {                      // prefetch next iter's sqn
#pragma unroll
            for (int sh = 0; sh < 2; ++sh) {
                nsq[sh * 2 + 0] = *(const float4*)&sqn[cb0 + (4 * (i + 1) + 2 * sh + tp) * 32 + kg * 4];
                nsq[sh * 2 + 1] = *(const float4*)&sqn[cb0 + (4 * (i + 1) + 2 * sh + tp) * 32 + 16 + kg * 4];
            }
        }

        // compute both supers of this iter
#pragma unroll
        for (int sh = 0; sh < 2; ++sh) {
            const unsigned short* fr = &U.ring[i & 1][sh][tp][0][0];
            bf16x8 A0 = *(const bf16x8*)(fr + 0 * 512 + lane * 8);   // st0 kh0
            bf16x8 A1 = *(const bf16x8*)(fr + 1 * 512 + lane * 8);   // st0 kh1
            bf16x8 A2 = *(const bf16x8*)(fr + 2 * 512 + lane * 8);   // st1 kh0
            bf16x8 A3 = *(const bf16x8*)(fr + 3 * 512 + lane * 8);   // st1 kh1

            f32x4 a00 = {sqc[sh * 2].x, sqc[sh * 2].y, sqc[sh * 2].z, sqc[sh * 2].w};
            f32x4 a01 = {0.f, 0.f, 0.f, 0.f};
            f32x4 a10 = {sqc[sh * 2 + 1].x, sqc[sh * 2 + 1].y, sqc[sh * 2 + 1].z, sqc[sh * 2 + 1].w};
            f32x4 a11 = {0.f, 0.f, 0.f, 0.f};
            a00 = __builtin_amdgcn_mfma_f32_16x16x32_bf16(A0, qhi0, a00, 0, 0, 0);
            a10 = __builtin_amdgcn_mfma_f32_16x16x32_bf16(A2, qhi0, a10, 0, 0, 0);
            a01 = __builtin_amdgcn_mfma_f32_16x16x32_bf16(A1, qhi1, a01, 0, 0, 0);
            a11 = __builtin_amdgcn_mfma_f32_16x16x32_bf16(A3, qhi1, a11, 0, 0, 0);
            a00 = __builtin_amdgcn_mfma_f32_16x16x32_bf16(A0, qlo0, a00, 0, 0, 0);
            a10 = __builtin_amdgcn_mfma_f32_16x16x32_bf16(A2, qlo0, a10, 0, 0, 0);
            a01 = __builtin_amdgcn_mfma_f32_16x16x32_bf16(A1, qlo1, a01, 0, 0, 0);
            a11 = __builtin_amdgcn_mfma_f32_16x16x32_bf16(A3, qlo1, a11, 0, 0, 0);

            int ibase = (4 * i + 2 * sh + tp) * 32 + kg * 4;
#pragma unroll
            for (int j = 0; j < 8; ++j) {
                float sc = (j < 4) ? -(a00[j & 3] + a01[j & 3]) : -(a10[j & 3] + a11[j & 3]);
                unsigned idx12 = (unsigned)(ibase + ((j >> 2) << 4) + (j & 3));
                float xv = __uint_as_float((__float_as_uint(sc) & 0xFFFFF000u) | idx12);
#pragma unroll
                for (int p = KNN - 1; p >= 1; --p)
                    kd[p] = __builtin_amdgcn_fmed3f(xv, kd[p - 1], kd[p]);
                kd[0] = fminf(kd[0], xv);
            }
        }

        __syncthreads();
#pragma unroll
        for (int q2 = 0; q2 < 4; ++q2) sqc[q2] = nsq[q2];
    }

    __syncthreads();   // ring dead; union repurposed as md/ci
#pragma unroll
    for (int p = 0; p < KNN; ++p) U.m.md[myq][(tp * 4 + kg) * KNN + p] = kd[p];
    __syncthreads();

    // merge 8 sorted lists -> top-RB packed (t<64)
    if (t < 64) {
        float kdm[RB];
#pragma unroll
        for (int s2 = 0; s2 < RB; ++s2) kdm[s2] = 3.4e38f;
        float km = 3.4e38f;
#pragma unroll 1
        for (int u = 0; u < 8; ++u) {
#pragma unroll 1
            for (int p = 0; p < KNN; ++p) {
                float d = U.m.md[t][u * KNN + p];
                if (d >= km) break;            // ascending list: rest can't qualify
#pragma unroll
                for (int s2 = RB - 1; s2 >= 1; --s2)
                    kdm[s2] = __builtin_amdgcn_fmed3f(d, kdm[s2 - 1], kdm[s2]);
                kdm[0] = fminf(kdm[0], d);
                km = kdm[RB - 1];
            }
        }
#pragma unroll
        for (int s2 = 0; s2 < RB; ++s2)
            U.m.ci[t][s2] = (int)(__float_as_uint(kdm[s2]) & 0xFFFu) + cb0;
    }
    __syncthreads();   // md dead; ce overlays it (ci persists at disjoint offset)

    // exact fp32 recheck: 64*RB = 1792 tasks over 512 threads (rows L1/L2-hot)
#pragma unroll 1
    for (int task = t; task < 64 * RB; task += 512) {
        int q = task / RB, sl = task - q * RB;
        int cidx = U.m.ci[q][sl];
        const float* xqp = x + (size_t)(n0 + q) * 64;
        const float* xc  = x + (size_t)cidx * 64;
        float dot = 0.f;
#pragma unroll
        for (int g = 0; g < 16; ++g) {
            float4 a = *(const float4*)(xqp + g * 4);
            float4 bb = *(const float4*)(xc + g * 4);
            dot += a.x * bb.x + a.y * bb.y + a.z * bb.z + a.w * bb.w;
        }
        U.r.ce[q][sl] = -sqn[cidx] - dot;     // = 0.5*sq - dot
    }
    __syncthreads();

    // drop the RB-KNN lexicographically-largest (score, then higher idx) -> exact top-20 set
    if (t < 64) {
        float ev[RB]; int iv[RB];
#pragma unroll
        for (int s2 = 0; s2 < RB; ++s2) { ev[s2] = U.r.ce[t][s2]; iv[s2] = U.m.ci[t][s2]; }
        unsigned mask = 0;
#pragma unroll
        for (int pass = 0; pass < RB - KNN; ++pass) {
            float best = -3.4e38f; int bid = -1, bs = 0;
#pragma unroll
            for (int s2 = 0; s2 < RB; ++s2) {
                bool free_ = ((mask >> s2) & 1u) == 0u;
                bool gt = (ev[s2] > best) || (ev[s2] == best && iv[s2] > bid);
                if (free_ && gt) { best = ev[s2]; bid = iv[s2]; bs = s2; }
            }
            mask |= 1u << bs;
        }
        int* op = knn_idx + (size_t)(n0 + t) * KNN;
        int pos = 0;
#pragma unroll
        for (int s2 = 0; s2 < RB; ++s2)
            if (((mask >> s2) & 1u) == 0u) op[pos++] = iv[s2];
    }
}

// ---------------- fused Yb = x@Wb (bf16) and out = x@Wres + bres ----------------
__global__ __launch_bounds__(256) void k_ybres(const unsigned short* __restrict__ xhi,
                                               const unsigned short* __restrict__ wb,
                                               const unsigned short* __restrict__ wrt,
                                               const float* __restrict__ bres,
                                               unsigned short* __restrict__ Yb,
                                               float* __restrict__ out) {
    int t = threadIdx.x;
    int wv = t >> 6, lane = t & 63;
    int lr = lane & 15, kg = lane >> 4;
    int n0 = blockIdx.x * 64 + wv * 16;

    bf16x8 af0 = *(const bf16x8*)(xhi + (size_t)(n0 + lr) * 64 + kg * 8);
    bf16x8 af1 = *(const bf16x8*)(xhi + (size_t)(n0 + lr) * 64 + 32 + kg * 8);

    f32x4 accY[8], accR[8];
#pragma unroll
    for (int nt = 0; nt < 8; ++nt) {
        accY[nt] = (f32x4){0.f, 0.f, 0.f, 0.f};
        float bv = bres[nt * 16 + lr];
        accR[nt] = (f32x4){bv, bv, bv, bv};
    }
#pragma unroll
    for (int nt = 0; nt < 8; ++nt) {
        bf16x8 b0 = *(const bf16x8*)(wb + (size_t)(nt * 16 + lr) * 64 + kg * 8);
        bf16x8 b1 = *(const bf16x8*)(wb + (size_t)(nt * 16 + lr) * 64 + 32 + kg * 8);
        accY[nt] = __builtin_amdgcn_mfma_f32_16x16x32_bf16(af0, b0, accY[nt], 0, 0, 0);
        accY[nt] = __builtin_amdgcn_mfma_f32_16x16x32_bf16(af1, b1, accY[nt], 0, 0, 0);
        bf16x8 r0 = *(const bf16x8*)(wrt + (size_t)(nt * 16 + lr) * 64 + kg * 8);
        bf16x8 r1 = *(const bf16x8*)(wrt + (size_t)(nt * 16 + lr) * 64 + 32 + kg * 8);
        accR[nt] = __builtin_amdgcn_mfma_f32_16x16x32_bf16(af0, r0, accR[nt], 0, 0, 0);
        accR[nt] = __builtin_amdgcn_mfma_f32_16x16x32_bf16(af1, r1, accR[nt], 0, 0, 0);
    }
#pragma unroll
    for (int nt = 0; nt < 8; ++nt)
#pragma unroll
        for (int j = 0; j < 4; ++j) {
            Yb[(size_t)(n0 + kg * 4 + j) * 128 + nt * 16 + lr] = f2bf(accY[nt][j]);
            out[(size_t)(n0 + kg * 4 + j) * 128 + nt * 16 + lr] = accR[nt][j];
        }
}

// ---------------- LN2 helper (C-frag layout; wave-local rows) ----------------
__device__ __forceinline__ void ln_relu_store(f32x4 acc[2][8], unsigned short* A, int wv, int lane,
                                              const float* __restrict__ bias, const float* __restrict__ g,
                                              const float* __restrict__ be) {
    int lc = lane & 15, kg = lane >> 4;
    float bv[8], gv[8], bev[8];
#pragma unroll
    for (int nt = 0; nt < 8; ++nt) {
        bv[nt]  = bias[nt * 16 + lc];
        gv[nt]  = g[nt * 16 + lc];
        bev[nt] = be[nt * 16 + lc];
    }
#pragma unroll
    for (int mt = 0; mt < 2; ++mt) {
#pragma unroll
        for (int j = 0; j < 4; ++j) {
            float v[8]; float s = 0.f, ss = 0.f;
#pragma unroll
            for (int nt = 0; nt < 8; ++nt) {
                v[nt] = acc[mt][nt][j] + bv[nt];
                s += v[nt]; ss += v[nt] * v[nt];
            }
#pragma unroll
            for (int m = 1; m < 16; m <<= 1) { s += __shfl_xor(s, m); ss += __shfl_xor(ss, m); }
            float mean = s * 0.0078125f;
            float var  = ss * 0.0078125f - mean * mean;
            float rstd = rsqrtf(fmaxf(var, 0.f) + 1e-5f);
            int row = wv * 32 + mt * 16 + kg * 4 + j;
#pragma unroll
            for (int nt = 0; nt < 8; ++nt) {
                float h = (v[nt] - mean) * rstd * gv[nt] + bev[nt];
                h = fmaxf(h, 0.f);
                A[(size_t)row * LDA + nt * 16 + lc] = f2bf(h);
            }
        }
    }
}

// ---------------- fused edge kernel (no GEMM1) ----------------
__global__ __launch_bounds__(320, 2) void k_edge(const float* __restrict__ x, const int* __restrict__ knn_idx,
                                                 const unsigned short* __restrict__ Yb,
                                                 const unsigned short* __restrict__ w2p,
                                                 const unsigned short* __restrict__ wa,
                                                 const float* __restrict__ b1, const float* __restrict__ g1, const float* __restrict__ be1,
                                                 const float* __restrict__ b2, const float* __restrict__ g2, const float* __restrict__ be2,
                                                 float* __restrict__ out) {
    __shared__ unsigned short A[160 * LDA];    // 43520 B: h1 -> h2
    __shared__ unsigned short W2s[32 * 512];   // 32768 B: W2 frag-packed
    __shared__ float Ya8[8][128];              // 4096 B
    __shared__ float GB[256];                  // g1 | be1
    int t = threadIdx.x;
    int bid = blockIdx.x;
    int blk = (bid & 7) * 512 + (bid >> 3);    // XCD swizzle: cloud-pinned

    for (int id = t; id < 2048; id += 320)
        *(uint4*)&W2s[id * 8] = *(const uint4*)(w2p + (size_t)id * 8);
    if (t < 32)       *(float4*)&GB[t * 4] = *(const float4*)(g1 + t * 4);
    else if (t < 64)  *(float4*)&GB[t * 4] = *(const float4*)(be1 + (t - 32) * 4);

    int r = t >> 1, h = t & 1;
    int eg = blk * 160 + r;
    int ploc = r / 20;
    int jn = knn_idx[eg];
    uint4 ybr[8];
    {
        const unsigned short* ybp = Yb + (size_t)jn * 128 + h * 64;
#pragma unroll
        for (int i = 0; i < 8; ++i) ybr[i] = *(const uint4*)(ybp + i * 8);
    }

    if (t < 64) {
        int lane = t, lr = lane & 15, kg = lane >> 4;
        int prow = blk * 8 + (lr & 7);
        const float* xp = x + (size_t)prow * 64;
        bf16x8 af0, af1;
        {
            union { unsigned short u[8]; bf16x8 v; } cv;
            float4 u0 = *(const float4*)(xp + kg * 8);
            float4 u1 = *(const float4*)(xp + kg * 8 + 4);
            cv.u[0] = f2bf(u0.x); cv.u[1] = f2bf(u0.y); cv.u[2] = f2bf(u0.z); cv.u[3] = f2bf(u0.w);
            cv.u[4] = f2bf(u1.x); cv.u[5] = f2bf(u1.y); cv.u[6] = f2bf(u1.z); cv.u[7] = f2bf(u1.w);
            af0 = cv.v;
            float4 w0 = *(const float4*)(xp + 32 + kg * 8);
            float4 w1 = *(const float4*)(xp + 32 + kg * 8 + 4);
            cv.u[0] = f2bf(w0.x); cv.u[1] = f2bf(w0.y); cv.u[2] = f2bf(w0.z); cv.u[3] = f2bf(w0.w);
            cv.u[4] = f2bf(w1.x); cv.u[5] = f2bf(w1.y); cv.u[6] = f2bf(w1.z); cv.u[7] = f2bf(w1.w);
            af1 = cv.v;
        }
        f32x4 accA[8];
#pragma unroll
        for (int nt = 0; nt < 8; ++nt) {
            float bv = b1[nt * 16 + lr];
            accA[nt] = (f32x4){bv, bv, bv, bv};
        }
#pragma unroll
        for (int nt = 0; nt < 8; ++nt) {
            bf16x8 b0 = *(const bf16x8*)(wa + (size_t)(nt * 16 + lr) * 64 + kg * 8);
            bf16x8 b1f = *(const bf16x8*)(wa + (size_t)(nt * 16 + lr) * 64 + 32 + kg * 8);
            accA[nt] = __builtin_amdgcn_mfma_f32_16x16x32_bf16(af0, b0, accA[nt], 0, 0, 0);
            accA[nt] = __builtin_amdgcn_mfma_f32_16x16x32_bf16(af1, b1f, accA[nt], 0, 0, 0);
        }
#pragma unroll
        for (int nt = 0; nt < 8; ++nt)
#pragma unroll
            for (int j = 0; j < 4; ++j) {
                int rr = kg * 4 + j;
                if (rr < 8) Ya8[rr][nt * 16 + lr] = accA[nt][j];
            }
    }
    __syncthreads();

    {
        float v[64]; float s = 0.f, ss = 0.f;
#pragma unroll
        for (int i = 0; i < 8; ++i) {
            unsigned uu[4] = {ybr[i].x, ybr[i].y, ybr[i].z, ybr[i].w};
#pragma unroll
            for (int k2 = 0; k2 < 4; ++k2) {
                int c = h * 64 + i * 8 + 2 * k2;
                float w0 = Ya8[ploc][c]     + bf2f((unsigned short)(uu[k2] & 0xFFFFu));
                float w1 = Ya8[ploc][c + 1] + bf2f((unsigned short)(uu[k2] >> 16));
                v[i * 8 + 2 * k2] = w0; v[i * 8 + 2 * k2 + 1] = w1;
                s += w0 + w1; ss += w0 * w0 + w1 * w1;
            }
        }
        s += __shfl_xor(s, 1); ss += __shfl_xor(ss, 1);
        float mean = s * 0.0078125f;
        float var  = ss * 0.0078125f - mean * mean;
        float rstd = rsqrtf(fmaxf(var, 0.f) + 1e-5f);
#pragma unroll
        for (int i = 0; i < 8; ++i) {
            unsigned short hh[8];
#pragma unroll
            for (int k2 = 0; k2 < 8; ++k2) {
                int c = h * 64 + i * 8 + k2;
                float hv = (v[i * 8 + k2] - mean) * rstd * GB[c] + GB[128 + c];
                hh[k2] = f2bf(fmaxf(hv, 0.f));
            }
            uint4 pk;
            pk.x = hh[0] | ((unsigned)hh[1] << 16); pk.y = hh[2] | ((unsigned)hh[3] << 16);
            pk.z = hh[4] | ((unsigned)hh[5] << 16); pk.w = hh[6] | ((unsigned)hh[7] << 16);
            *(uint4*)&A[(size_t)r * LDA + h * 64 + i * 8] = pk;
        }
    }

    int wv = t >> 6, lane = t & 63;
    int lr = lane & 15, kg = lane >> 4;
    f32x4 acc2[2][8];
#pragma unroll
    for (int i = 0; i < 2; ++i)
#pragma unroll
        for (int j = 0; j < 8; ++j) acc2[i][j] = (f32x4){0.f, 0.f, 0.f, 0.f};
#pragma unroll
    for (int ks = 0; ks < 4; ++ks) {
        int ko = ks * 32 + kg * 8;
        bf16x8 a0 = *(const bf16x8*)(A + (size_t)(wv * 32 + lr) * LDA + ko);
        bf16x8 a1 = *(const bf16x8*)(A + (size_t)(wv * 32 + 16 + lr) * LDA + ko);
#pragma unroll
        for (int nt = 0; nt < 8; ++nt) {
            bf16x8 bf = *(const bf16x8*)&W2s[(size_t)(ks * 8 + nt) * 512 + lane * 8];
            acc2[0][nt] = __builtin_amdgcn_mfma_f32_16x16x32_bf16(a0, bf, acc2[0][nt], 0, 0, 0);
            acc2[1][nt] = __builtin_amdgcn_mfma_f32_16x16x32_bf16(a1, bf, acc2[1][nt], 0, 0, 0);
        }
    }
    ln_relu_store(acc2, A, wv, lane, b2, g2, be2);

    __syncthreads();

    if (t < 128) {
        int p = t >> 4, cg = t & 15;
        int n = blk * 8 + p;
        float mx[8];
#pragma unroll
        for (int k = 0; k < 8; ++k) mx[k] = 0.f;
#pragma unroll
        for (int rr = 0; rr < 20; ++rr) {
            uint4 vv = *(const uint4*)&A[(size_t)(p * 20 + rr) * LDA + cg * 8];
            unsigned uu[4] = {vv.x, vv.y, vv.z, vv.w};
#pragma unroll
            for (int k = 0; k < 4; ++k) {
                float lo = __uint_as_float(uu[k] << 16);
                float hi = __uint_as_float(uu[k] & 0xFFFF0000u);
                mx[2 * k]     = fmaxf(mx[2 * k], lo);
                mx[2 * k + 1] = fmaxf(mx[2 * k + 1], hi);
            }
        }
        float* op = out + (size_t)n * 128 + cg * 8;
        float4 o0 = *(float4*)op;
        float4 o1 = *(float4*)(op + 4);
        o0.x += mx[0]; o0.y += mx[1]; o0.z += mx[2]; o0.w += mx[3];
        o1.x += mx[4]; o1.y += mx[5]; o1.z += mx[6]; o1.w += mx[7];
        *(float4*)op = o0;
        *(float4*)(op + 4) = o1;
    }
}

// ---------------- launcher ----------------
extern "C" void kernel_launch(void* const* d_in, const int* in_sizes, int n_in,
                              void* d_out, int out_size, void* d_ws, size_t ws_size,
                              hipStream_t stream) {
    const float* x    = (const float*)d_in[0];
    const float* W1   = (const float*)d_in[2];
    const float* b1   = (const float*)d_in[3];
    const float* g1   = (const float*)d_in[4];
    const float* be1  = (const float*)d_in[5];
    const float* W2   = (const float*)d_in[6];
    const float* b2   = (const float*)d_in[7];
    const float* g2   = (const float*)d_in[8];
    const float* be2  = (const float*)d_in[9];
    const float* Wres = (const float*)d_in[10];
    const float* bres = (const float*)d_in[11];
    float* out = (float*)d_out;

    char* ws = (char*)d_ws;
    float* sqn           = (float*)(ws);                     // 131072 B
    unsigned short* wa   = (unsigned short*)(ws + 131072);   // 16384 B
    unsigned short* wb   = (unsigned short*)(ws + 147456);   // 16384 B
    unsigned short* wrt  = (unsigned short*)(ws + 163840);   // 16384 B
    unsigned short* w2p  = (unsigned short*)(ws + 180224);   // 32768 B
    int* knn_idx         = (int*)(ws + 212992);              // 2621440 B
    unsigned short* Yb   = (unsigned short*)(ws + 2834432);  // 8388608 B -> end 11223040

    unsigned short* xhi = (unsigned short*)d_out;                       // 4 MB
    unsigned short* xlo = (unsigned short*)((char*)d_out + 4194304);    // 4 MB

    k_prep  <<<dim3(1024),      dim3(256), 0, stream>>>(x, xhi, xlo, sqn);
    k_wt    <<<dim3(160),       dim3(256), 0, stream>>>(W1, W2, Wres, wa, wb, wrt, w2p);
    k_knn   <<<dim3(NB * 64),   dim3(512), 0, stream>>>(x, xhi, xlo, sqn, knn_idx);
    k_ybres <<<dim3(NTOT / 64), dim3(256), 0, stream>>>(xhi, wb, wrt, bres, Yb, out);
    k_edge  <<<dim3(NEDGE / 160), dim3(320), 0, stream>>>(x, knn_idx, Yb, w2p, wa,
                                                          b1, g1, be1, b2, g2, be2, out);
}